// Round 7
// baseline (240.467 us; speedup 1.0000x reference)
//
#include <hip/hip_runtime.h>
#include <hip/hip_bf16.h>
#include <stdint.h>

#define T_DIM 4096
#define H_DIM 1024
#define I_DIM 2048

typedef __bf16 bf16x8 __attribute__((ext_vector_type(8)));
typedef float f32x4 __attribute__((ext_vector_type(4)));
typedef unsigned short ushort_t;
typedef unsigned short us4 __attribute__((ext_vector_type(4)));

__device__ __forceinline__ unsigned short f32_to_bf16(float f) {
  unsigned int u = __float_as_uint(f);
  u += 0x7fffu + ((u >> 16) & 1u);  // RNE
  return (unsigned short)(u >> 16);
}

__device__ __forceinline__ void gload_lds16(const void* g, void* l) {
  __builtin_amdgcn_global_load_lds(
      (__attribute__((address_space(1))) void*)(uintptr_t)g,
      (__attribute__((address_space(3))) void*)(unsigned int)(uintptr_t)l,
      16, 0, 0);
}

// XOR swizzle on byte offsets within an 8KB B-panel (involution; bits 7-9
// untouched). Verified R4: bank conflicts 6.29M -> 0 with this exact pattern.
__device__ __forceinline__ int swz(int L) { return L ^ (((L >> 7) & 7) << 4); }

#define S_BARRIER() asm volatile("s_barrier" ::: "memory")
#define WAITV(n) asm volatile("s_waitcnt vmcnt(" #n ")" ::: "memory")
#define IRFENCE() asm volatile("" ::: "memory")
#define MFMA16(acc, va, vb) \
  acc = __builtin_amdgcn_mfma_f32_16x16x32_bf16(va, vb, acc, 0, 0, 0)

// ------- rmsnorm + out-init fused ---------------------------------------------
__global__ __launch_bounds__(256) void k_rmsnorm_init(
    const float* __restrict__ x, const float* __restrict__ scale,
    const float* __restrict__ b2, ushort_t* __restrict__ normed,
    float* __restrict__ out) {
  const int row = blockIdx.x, tid = threadIdx.x;
  const float4 v = ((const float4*)(x + (size_t)row * H_DIM))[tid];
  float ss = v.x * v.x + v.y * v.y + v.z * v.z + v.w * v.w;
#pragma unroll
  for (int off = 32; off > 0; off >>= 1) ss += __shfl_xor(ss, off);
  __shared__ float wsum[4];
  if ((tid & 63) == 0) wsum[tid >> 6] = ss;
  __syncthreads();
  const float tot = wsum[0] + wsum[1] + wsum[2] + wsum[3];
  const float inv = rsqrtf(tot * (1.0f / H_DIM) + 1e-5f);
  const float4 sc = ((const float4*)scale)[tid];
  us4 o;
  o.x = f32_to_bf16(v.x * inv * sc.x);
  o.y = f32_to_bf16(v.y * inv * sc.y);
  o.z = f32_to_bf16(v.z * inv * sc.z);
  o.w = f32_to_bf16(v.w * inv * sc.w);
  ((us4*)(normed + (size_t)row * H_DIM))[tid] = o;
  const float4 b0 = ((const float4*)b2)[tid];
  const float4 b1 = ((const float4*)(b2 + H_DIM))[tid];
  float4 ov;
  ov.x = v.x + 0.5f * (b0.x + b1.x);
  ov.y = v.y + 0.5f * (b0.y + b1.y);
  ov.z = v.z + 0.5f * (b0.z + b1.z);
  ov.w = v.w + 0.5f * (b0.w + b1.w);
  ((float4*)(out + (size_t)row * H_DIM))[tid] = ov;
}

// ------- transpose+convert: src[R][C] f32 -> dst[C][R] bf16 (per blockIdx.z) ---
__global__ __launch_bounds__(256) void k_transpose_cvt(const float* __restrict__ src,
                                                       ushort_t* __restrict__ dst,
                                                       int R, int C) {
  __shared__ float tile[32][33];
  const size_t eoff = (size_t)blockIdx.z * (size_t)R * (size_t)C;
  src += eoff;
  dst += eoff;
  const int x0 = blockIdx.x * 32, y0 = blockIdx.y * 32;
  const int tx = threadIdx.x & 31, ty = threadIdx.x >> 5;
#pragma unroll
  for (int i = 0; i < 4; ++i)
    tile[ty + 8 * i][tx] = src[(size_t)(y0 + ty + 8 * i) * C + x0 + tx];
  __syncthreads();
#pragma unroll
  for (int i = 0; i < 4; ++i)
    dst[(size_t)(x0 + ty + 8 * i) * R + y0 + tx] = f32_to_bf16(tile[tx][ty + 8 * i]);
}

// ---------------- GEMM1: A from GLOBAL (direct per-lane 16B loads), B in LDS ---
// Block 256 rows x (128 gate + 128 linear). BK=64 in 2 halves. LDS holds B only:
// [buf][ks]{gate 8KB, linear 8KB} = 64 KiB total. A-fragment loads hit L1/L2
// (2x wn-duplication only); B (4x wm-dup) stays staged. Cuts LDS bytes 37%.
__global__ __launch_bounds__(512, 2) void k_gemm1(
    const ushort_t* __restrict__ normed, const ushort_t* __restrict__ w1T,
    const float* __restrict__ b1, ushort_t* __restrict__ act) {
  __shared__ __align__(16) ushort_t lds[2][2][8192];  // 64 KiB, B panels only
  char* const ldsB = (char*)&lds[0][0][0];
  const int tid = threadIdx.x;
  const int wg = (blockIdx.x & 7) * 64 + (blockIdx.x >> 3);  // XCD swizzle
  const int e = wg >> 8;
  const int rem = wg & 255;
  const int brow = (rem >> 4) * 256;
  const int bcol = (rem & 15) * 128;
  const int lane = tid & 63;
  const int wm = (tid >> 6) >> 1;
  const int wn = (tid >> 6) & 1;
  const int r16 = lane & 15, kh = lane >> 4;

  const ushort_t* gBase = w1T + ((size_t)e * 2 * I_DIM + bcol) * H_DIM;
  const ushort_t* lBase = gBase + (size_t)I_DIM * H_DIM;

  f32x4 accg[4][4], accl[4][4];
  const f32x4 zf = {0.f, 0.f, 0.f, 0.f};
#pragma unroll
  for (int m = 0; m < 4; ++m)
#pragma unroll
    for (int n = 0; n < 4; ++n) { accg[m][n] = zf; accl[m][n] = zf; }

  // B staging decomposition (pre-swizzled source, linear LDS dest — rule 21).
  int srow[2], scolb[2];
#pragma unroll
  for (int j = 0; j < 2; ++j) {
    const int u = swz((j * 512 + tid) * 16);
    srow[j] = u >> 6;
    scolb[j] = (u & 63) >> 1;
  }
  const int ldst0 = (tid & ~63) * 16;  // 0..7168 bytes within an 8KB panel

  // Running pointers: pG/pL stage the NEXT tile; pA reads the CURRENT tile.
  const ushort_t* pG = gBase + (size_t)srow[0] * H_DIM + scolb[0];
  const ushort_t* pL = lBase + (size_t)(srow[1] - 128) * H_DIM + scolb[1];
  const ushort_t* pA = normed + (size_t)(brow + wm * 64 + r16) * H_DIM + kh * 8;

  int boffV[2][4];
#pragma unroll
  for (int bq = 0; bq < 2; ++bq)
#pragma unroll
    for (int n = 0; n < 4; ++n)
      boffV[bq][n] = bq * 32768 + swz((wn * 64 + n * 16 + r16) * 64 + kh * 16);

  auto stageB = [&](int buf, int ksub) {
    gload_lds16(pG + ksub * 32, ldsB + buf * 32768 + ksub * 16384 + ldst0);
    gload_lds16(pL + ksub * 32, ldsB + buf * 32768 + ksub * 16384 + 8192 + ldst0);
  };
  auto rdBg = [&](int buf, int ksub, int n) -> bf16x8 {
    return *(const bf16x8*)(ldsB + boffV[buf][n] + ksub * 16384);
  };
  auto rdBl = [&](int buf, int ksub, int n) -> bf16x8 {
    return *(const bf16x8*)(ldsB + boffV[buf][n] + ksub * 16384 + 8192);
  };
  auto ldA = [&](int ksub, int m) -> bf16x8 {
    return *(const bf16x8*)(pA + (size_t)m * 16 * H_DIM + ksub * 32);
  };

#define G1_ADV() \
  { pA += 64; pG += 64; pL += 64; }

  // One K-half: A issued first (stays in flight past stage), stage next tile,
  // MFMA (compiler auto-waits vmcnt(2): A drained, stage kept in flight),
  // then the one load-bearing WAITV(2)+barrier (drains unit staged last tile).
#define G1_HALF(CUR, NXT, KS)                                                 \
  {                                                                           \
    _Pragma("unroll") for (int m = 0; m < 4; ++m) a[m] = ldA(KS, m);          \
    IRFENCE();                                                                \
    _Pragma("unroll") for (int n = 0; n < 4; ++n) b[n] = rdBg(CUR, KS, n);    \
    stageB(NXT, KS);                                                          \
    __builtin_amdgcn_s_setprio(1);                                            \
    _Pragma("unroll") for (int m = 0; m < 4; ++m)                             \
        _Pragma("unroll") for (int n = 0; n < 4; ++n)                         \
            MFMA16(accg[m][n], a[m], b[n]);                                   \
    __builtin_amdgcn_s_setprio(0);                                            \
    _Pragma("unroll") for (int n = 0; n < 4; ++n) b[n] = rdBl(CUR, KS, n);    \
    __builtin_amdgcn_s_setprio(1);                                            \
    _Pragma("unroll") for (int m = 0; m < 4; ++m)                             \
        _Pragma("unroll") for (int n = 0; n < 4; ++n)                         \
            MFMA16(accl[m][n], a[m], b[n]);                                   \
    __builtin_amdgcn_s_setprio(0);                                            \
    WAITV(2);                                                                 \
    S_BARRIER();                                                              \
  }

#define G1_TILE(CUR, NXT)  \
  { G1_HALF(CUR, NXT, 0); G1_HALF(CUR, NXT, 1); G1_ADV(); }

  // Prologue: stage tile 0 (B only); advance stage pointers to tile 1 (pA stays).
  stageB(0, 0); IRFENCE();
  stageB(0, 1);
  pG += 64; pL += 64;
  WAITV(2);  // half-0 panel landed; half-1 pair stays in flight
  S_BARRIER();

  bf16x8 a[4], b[4];
#pragma unroll 1
  for (int it = 0; it < 7; ++it) {  // tiles 0..13
    G1_TILE(0, 1);
    G1_TILE(1, 0);
  }
  G1_TILE(0, 1);  // tile 14, stages tile 15 into buf1

  // Tail: tile 15 in buf1 (half0 drained; half1 pair in flight).
  {
#pragma unroll
    for (int m = 0; m < 4; ++m) a[m] = ldA(0, m);
#pragma unroll
    for (int n = 0; n < 4; ++n) b[n] = rdBg(1, 0, n);
#pragma unroll
    for (int m = 0; m < 4; ++m)
#pragma unroll
      for (int n = 0; n < 4; ++n) MFMA16(accg[m][n], a[m], b[n]);
#pragma unroll
    for (int n = 0; n < 4; ++n) b[n] = rdBl(1, 0, n);
#pragma unroll
    for (int m = 0; m < 4; ++m)
#pragma unroll
      for (int n = 0; n < 4; ++n) MFMA16(accl[m][n], a[m], b[n]);
    WAITV(0);
    S_BARRIER();  // all waves' half-1 staging drained
#pragma unroll
    for (int m = 0; m < 4; ++m) a[m] = ldA(1, m);
#pragma unroll
    for (int n = 0; n < 4; ++n) b[n] = rdBg(1, 1, n);
#pragma unroll
    for (int m = 0; m < 4; ++m)
#pragma unroll
      for (int n = 0; n < 4; ++n) MFMA16(accg[m][n], a[m], b[n]);
#pragma unroll
    for (int n = 0; n < 4; ++n) b[n] = rdBl(1, 1, n);
#pragma unroll
    for (int m = 0; m < 4; ++m)
#pragma unroll
      for (int n = 0; n < 4; ++n) MFMA16(accl[m][n], a[m], b[n]);
  }
#undef G1_HALF
#undef G1_TILE
#undef G1_ADV

  // Epilogue: bias + clip + sigmoid-gate, store bf16 act.
  const float* b1e = b1 + (size_t)e * 2 * I_DIM;
#pragma unroll
  for (int m = 0; m < 4; ++m)
#pragma unroll
    for (int n = 0; n < 4; ++n) {
      const int gcol = bcol + wn * 64 + n * 16 + r16;
      const float bgb = b1e[gcol];
      const float blb = b1e[I_DIM + gcol];
#pragma unroll
      for (int rr = 0; rr < 4; ++rr) {
        const int grow = brow + wm * 64 + m * 16 + kh * 4 + rr;
        const float hg = accg[m][n][rr] + bgb;
        const float hl = accl[m][n][rr] + blb;
        const float g = fminf(hg, 7.f);
        const float l = fminf(fmaxf(hl, -7.f), 7.f);
        const float s = 1.f / (1.f + __expf(-1.702f * g));
        const float av = g * s * (l + 1.f);
        act[((size_t)e * T_DIM + grow) * I_DIM + gcol] = f32_to_bf16(av);
      }
    }
}

// ---------------- GEMM2: A(act) from GLOBAL, W2 in LDS; split-K=2 by expert ----
// Block 256x128, 8 waves, wave 64x64. LDS = [buf][ks] 8KB W2 panel = 32 KiB.
__global__ __launch_bounds__(512, 2) void k_gemm2(
    const ushort_t* __restrict__ act, const ushort_t* __restrict__ w2T,
    float* __restrict__ out) {
  __shared__ __align__(16) ushort_t lds[2][2][4096];  // 32 KiB
  char* const ldsB = (char*)&lds[0][0][0];
  const int tid = threadIdx.x;
  const int wg = (blockIdx.x & 7) * 32 + (blockIdx.x >> 3);
  const int e = wg >> 7;
  const int tileid = wg & 127;
  const int brow = (tileid >> 3) * 256;
  const int bcol = (tileid & 7) * 128;
  const int lane = tid & 63;
  const int wm = (tid >> 6) >> 1;
  const int wn = (tid >> 6) & 1;
  const int r16 = lane & 15, kh = lane >> 4;

  const ushort_t* bBase = w2T + ((size_t)e * H_DIM + bcol) * I_DIM;

  f32x4 acc[4][4];
  const f32x4 zf = {0.f, 0.f, 0.f, 0.f};
#pragma unroll
  for (int m = 0; m < 4; ++m)
#pragma unroll
    for (int n = 0; n < 4; ++n) acc[m][n] = zf;

  const int u0 = swz(tid * 16);
  const int srow0 = u0 >> 6;
  const int scolb0 = (u0 & 63) >> 1;
  const int ldst0 = (tid & ~63) * 16;

  const ushort_t* pB = bBase + (size_t)srow0 * I_DIM + scolb0;
  const ushort_t* pA = act + ((size_t)e * T_DIM + brow + wm * 64 + r16) * I_DIM + kh * 8;

  int boffV[2][4];
#pragma unroll
  for (int bq = 0; bq < 2; ++bq)
#pragma unroll
    for (int n = 0; n < 4; ++n)
      boffV[bq][n] = bq * 16384 + swz((wn * 64 + n * 16 + r16) * 64 + kh * 16);

  auto stageB = [&](int buf, int ksub) {
    gload_lds16(pB + ksub * 32, ldsB + buf * 16384 + ksub * 8192 + ldst0);
  };
  auto rdB = [&](int buf, int ksub, int n) -> bf16x8 {
    return *(const bf16x8*)(ldsB + boffV[buf][n] + ksub * 8192);
  };
  auto ldA = [&](int ksub, int m) -> bf16x8 {
    return *(const bf16x8*)(pA + (size_t)m * 16 * I_DIM + ksub * 32);
  };

#define G2_ADV() \
  { pA += 64; pB += 64; }

#define G2_HALF(CUR, NXT, KS)                                                 \
  {                                                                           \
    _Pragma("unroll") for (int m = 0; m < 4; ++m) a[m] = ldA(KS, m);          \
    IRFENCE();                                                                \
    _Pragma("unroll") for (int n = 0; n < 4; ++n) b[n] = rdB(CUR, KS, n);     \
    stageB(NXT, KS);                                                          \
    __builtin_amdgcn_s_setprio(1);                                            \
    _Pragma("unroll") for (int m = 0; m < 4; ++m)                             \
        _Pragma("unroll") for (int n = 0; n < 4; ++n)                         \
            MFMA16(acc[m][n], a[m], b[n]);                                    \
    __builtin_amdgcn_s_setprio(0);                                            \
    WAITV(1);                                                                 \
    S_BARRIER();                                                              \
  }

#define G2_TILE(CUR, NXT)  \
  { G2_HALF(CUR, NXT, 0); G2_HALF(CUR, NXT, 1); G2_ADV(); }

  // Prologue.
  stageB(0, 0); IRFENCE();
  stageB(0, 1);
  pB += 64;
  WAITV(1);
  S_BARRIER();

  bf16x8 a[4], b[4];
#pragma unroll 1
  for (int it = 0; it < 15; ++it) {  // tiles 0..29
    G2_TILE(0, 1);
    G2_TILE(1, 0);
  }
  G2_TILE(0, 1);  // tile 30, stages 31 into buf1

  // Tail: tile 31 in buf1.
  {
#pragma unroll
    for (int m = 0; m < 4; ++m) a[m] = ldA(0, m);
#pragma unroll
    for (int n = 0; n < 4; ++n) b[n] = rdB(1, 0, n);
#pragma unroll
    for (int m = 0; m < 4; ++m)
#pragma unroll
      for (int n = 0; n < 4; ++n) MFMA16(acc[m][n], a[m], b[n]);
    WAITV(0);
    S_BARRIER();
#pragma unroll
    for (int m = 0; m < 4; ++m) a[m] = ldA(1, m);
#pragma unroll
    for (int n = 0; n < 4; ++n) b[n] = rdB(1, 1, n);
#pragma unroll
    for (int m = 0; m < 4; ++m)
#pragma unroll
      for (int n = 0; n < 4; ++n) MFMA16(acc[m][n], a[m], b[n]);
  }
#undef G2_HALF
#undef G2_TILE
#undef G2_ADV

  // Epilogue: atomic accumulate 0.5*acc into out (pre-initialized x + bias).
#pragma unroll
  for (int m = 0; m < 4; ++m)
#pragma unroll
    for (int n = 0; n < 4; ++n) {
      const int gcol = bcol + wn * 64 + n * 16 + r16;
#pragma unroll
      for (int rr = 0; rr < 4; ++rr) {
        const int grow = brow + wm * 64 + m * 16 + kh * 4 + rr;
        atomicAdd(&out[(size_t)grow * H_DIM + gcol], 0.5f * acc[m][n][rr]);
      }
    }
}

extern "C" void kernel_launch(void* const* d_in, const int* in_sizes, int n_in,
                              void* d_out, int out_size, void* d_ws, size_t ws_size,
                              hipStream_t stream) {
  const float* x = (const float*)d_in[0];
  const float* scale = (const float*)d_in[1];
  // d_in[2]=gate_kernel, d_in[3]=gate_bias: static routing, logits unused.
  const float* w1 = (const float*)d_in[4];
  const float* b1 = (const float*)d_in[5];
  const float* w2 = (const float*)d_in[6];
  const float* b2 = (const float*)d_in[7];
  float* out = (float*)d_out;

  ushort_t* ws = (ushort_t*)d_ws;
  ushort_t* normed = ws;                                    // [T][H]
  ushort_t* w1T = normed + (size_t)T_DIM * H_DIM;           // [2][2I][H]
  ushort_t* w2T = w1T + (size_t)2 * 2 * I_DIM * H_DIM;      // [2][H][I]
  ushort_t* actb = w2T + (size_t)2 * H_DIM * I_DIM;         // [2][T][I]

  k_rmsnorm_init<<<dim3(T_DIM), 256, 0, stream>>>(x, scale, b2, normed, out);
  k_transpose_cvt<<<dim3(2 * I_DIM / 32, H_DIM / 32, 2), 256, 0, stream>>>(
      w1, w1T, H_DIM, 2 * I_DIM);
  k_transpose_cvt<<<dim3(H_DIM / 32, I_DIM / 32, 2), 256, 0, stream>>>(
      w2, w2T, I_DIM, H_DIM);
  k_gemm1<<<dim3(512), 512, 0, stream>>>(normed, w1T, b1, actb);
  k_gemm2<<<dim3(256), 512, 0, stream>>>(actb, w2T, out);
}

// Round 8
// 153.447 us; speedup vs baseline: 1.5671x; 1.5671x over previous
//
#include <hip/hip_runtime.h>
#include <hip/hip_bf16.h>
#include <stdint.h>

#define T_DIM 4096
#define H_DIM 1024
#define I_DIM 2048

typedef __bf16 bf16x8 __attribute__((ext_vector_type(8)));
typedef float f32x4 __attribute__((ext_vector_type(4)));
typedef unsigned short ushort_t;
typedef unsigned short us4 __attribute__((ext_vector_type(4)));

__device__ __forceinline__ unsigned short f32_to_bf16(float f) {
  unsigned int u = __float_as_uint(f);
  u += 0x7fffu + ((u >> 16) & 1u);  // RNE
  return (unsigned short)(u >> 16);
}

__device__ __forceinline__ void gload_lds16(const void* g, void* l) {
  __builtin_amdgcn_global_load_lds(
      (__attribute__((address_space(1))) void*)(uintptr_t)g,
      (__attribute__((address_space(3))) void*)(unsigned int)(uintptr_t)l,
      16, 0, 0);
}

// XOR swizzle (involution, bits 4-6 ^= bits 7-9). Verified R4: conflicts -> 0.
// Key property: transparent to adds of multiples of 1024 (no carry into bits
// 7-9 from our row arithmetic) -> fragment addrs = ONE VGPR + literal offset.
__device__ __forceinline__ int swz(int L) { return L ^ (((L >> 7) & 7) << 4); }

#define S_BARRIER() asm volatile("s_barrier" ::: "memory")
#define WAITV(n) asm volatile("s_waitcnt vmcnt(" #n ")" ::: "memory")
#define LGKM0() asm volatile("s_waitcnt lgkmcnt(0)" ::: "memory")
#define SCHEDB() __builtin_amdgcn_sched_barrier(0)
#define IRFENCE() asm volatile("" ::: "memory")
#define MFMA16(acc, va, vb) \
  acc = __builtin_amdgcn_mfma_f32_16x16x32_bf16(va, vb, acc, 0, 0, 0)

// ------- rmsnorm + out-init fused ---------------------------------------------
__global__ __launch_bounds__(256) void k_rmsnorm_init(
    const float* __restrict__ x, const float* __restrict__ scale,
    const float* __restrict__ b2, ushort_t* __restrict__ normed,
    float* __restrict__ out) {
  const int row = blockIdx.x, tid = threadIdx.x;
  const float4 v = ((const float4*)(x + (size_t)row * H_DIM))[tid];
  float ss = v.x * v.x + v.y * v.y + v.z * v.z + v.w * v.w;
#pragma unroll
  for (int off = 32; off > 0; off >>= 1) ss += __shfl_xor(ss, off);
  __shared__ float wsum[4];
  if ((tid & 63) == 0) wsum[tid >> 6] = ss;
  __syncthreads();
  const float tot = wsum[0] + wsum[1] + wsum[2] + wsum[3];
  const float inv = rsqrtf(tot * (1.0f / H_DIM) + 1e-5f);
  const float4 sc = ((const float4*)scale)[tid];
  us4 o;
  o.x = f32_to_bf16(v.x * inv * sc.x);
  o.y = f32_to_bf16(v.y * inv * sc.y);
  o.z = f32_to_bf16(v.z * inv * sc.z);
  o.w = f32_to_bf16(v.w * inv * sc.w);
  ((us4*)(normed + (size_t)row * H_DIM))[tid] = o;
  const float4 b0 = ((const float4*)b2)[tid];
  const float4 b1 = ((const float4*)(b2 + H_DIM))[tid];
  float4 ov;
  ov.x = v.x + 0.5f * (b0.x + b1.x);
  ov.y = v.y + 0.5f * (b0.y + b1.y);
  ov.z = v.z + 0.5f * (b0.z + b1.z);
  ov.w = v.w + 0.5f * (b0.w + b1.w);
  ((float4*)(out + (size_t)row * H_DIM))[tid] = ov;
}

// ------- transpose+convert: src[R][C] f32 -> dst[C][R] bf16 (per blockIdx.z) ---
__global__ __launch_bounds__(256) void k_transpose_cvt(const float* __restrict__ src,
                                                       ushort_t* __restrict__ dst,
                                                       int R, int C) {
  __shared__ float tile[32][33];
  const size_t eoff = (size_t)blockIdx.z * (size_t)R * (size_t)C;
  src += eoff;
  dst += eoff;
  const int x0 = blockIdx.x * 32, y0 = blockIdx.y * 32;
  const int tx = threadIdx.x & 31, ty = threadIdx.x >> 5;
#pragma unroll
  for (int i = 0; i < 4; ++i)
    tile[ty + 8 * i][tx] = src[(size_t)(y0 + ty + 8 * i) * C + x0 + tx];
  __syncthreads();
#pragma unroll
  for (int i = 0; i < 4; ++i)
    dst[(size_t)(x0 + ty + 8 * i) * R + y0 + tx] = f32_to_bf16(tile[tx][ty + 8 * i]);
}

// ---------------- GEMM1: 256 rows x 128 pair-cols, m201-style 4-phase K-tiles --
// 8 waves as 2(wm: 128 rows) x 4(wn: 32 gate + 32 linear cols). Per-wave
// 128x(32g+32l), acc 8x(2+2) frags. Phase (mq,ks): read 4 A-frags (+4 B at
// mq=0, held in regs), stage 1 unit, barrier, lgkm(0), 16 MFMA, barrier.
// WAITV(4) at the two k-half boundaries (ring verified R4). LDS 128KB.
__global__ __launch_bounds__(512, 2) void k_gemm1(
    const ushort_t* __restrict__ normed, const ushort_t* __restrict__ w1T,
    const float* __restrict__ b1, ushort_t* __restrict__ act) {
  __shared__ __align__(16) ushort_t lds[2][4][8192];  // 128 KiB
  char* const ldsB = (char*)&lds[0][0][0];
  const int tid = threadIdx.x;
  const int wg = (blockIdx.x & 7) * 64 + (blockIdx.x >> 3);  // XCD swizzle
  const int e = wg >> 8;
  const int rem = wg & 255;
  const int brow = (rem >> 4) * 256;
  const int bcol = (rem & 15) * 128;
  const int lane = tid & 63;
  const int wid = tid >> 6;
  const int wm = wid >> 2;   // 0..1 -> 128 rows
  const int wn = wid & 3;    // 0..3 -> 32 gate + 32 linear cols
  const int r16 = lane & 15, kh = lane >> 4;

  const ushort_t* gBase = w1T + ((size_t)e * 2 * I_DIM + bcol) * H_DIM;
  const ushort_t* lBase = gBase + (size_t)I_DIM * H_DIM;

  f32x4 accg[8][2], accl[8][2];
  const f32x4 zf = {0.f, 0.f, 0.f, 0.f};
#pragma unroll
  for (int m = 0; m < 8; ++m)
#pragma unroll
    for (int n = 0; n < 2; ++n) { accg[m][n] = zf; accl[m][n] = zf; }

  // Staging decomposition (pre-swizzled source, linear LDS dest — rule 21).
  int srow[2], scolb[2];
#pragma unroll
  for (int j = 0; j < 2; ++j) {
    const int u = swz((j * 512 + tid) * 16);
    srow[j] = u >> 6;
    scolb[j] = (u & 63) >> 1;
  }
  const int ldst0 = (tid & ~63) * 16;

  const ushort_t* pA0 = normed + (size_t)(brow + srow[0]) * H_DIM + scolb[0];
  const ushort_t* pA1 = normed + (size_t)(brow + srow[1]) * H_DIM + scolb[1];
  const ushort_t* pG = gBase + (size_t)srow[0] * H_DIM + scolb[0];
  const ushort_t* pL = lBase + (size_t)(srow[1] - 128) * H_DIM + scolb[1];

  // Single-VGPR fragment bases (swizzle transparent to +1024*m / +4096*mq /
  // +32768*ks — all folded into ds_read offset immediates).
  int avo[2], bvo[2];
  {
    const int abase = swz((wm * 128 + r16) * 64 + kh * 16);
    const int bbase = 16384 + swz((wn * 32 + r16) * 64 + kh * 16);
#pragma unroll
    for (int bq = 0; bq < 2; ++bq) {
      avo[bq] = bq * 65536 + abase;
      bvo[bq] = bq * 65536 + bbase;
    }
  }

  auto stageA = [&](int buf, int ks) {
    gload_lds16(pA0 + ks * 32, ldsB + buf * 65536 + ks * 32768 + ldst0);
    gload_lds16(pA1 + ks * 32, ldsB + buf * 65536 + ks * 32768 + 8192 + ldst0);
  };
  auto stageB = [&](int buf, int ks) {
    gload_lds16(pG + ks * 32, ldsB + buf * 65536 + ks * 32768 + 16384 + ldst0);
    gload_lds16(pL + ks * 32, ldsB + buf * 65536 + ks * 32768 + 16384 + 8192 + ldst0);
  };

#define G1_ADV() \
  { pA0 += 64; pA1 += 64; pG += 64; pL += 64; }

  // Phase pair for one k-half KS of buffer C (staging into N):
  //   mq=0: 4 A reads + 4 B reads (held), stage A; mq=1: 4 A reads, stage B.
#define G1_KHALF(C, N, KS)                                                    \
  {                                                                           \
    _Pragma("unroll") for (int m = 0; m < 4; ++m)                             \
        a[m] = *(const bf16x8*)(ldsB + avo[C] + KS * 32768 + m * 1024);       \
    _Pragma("unroll") for (int n = 0; n < 2; ++n) {                           \
      bg[n] = *(const bf16x8*)(ldsB + bvo[C] + KS * 32768 + n * 1024);        \
      bl[n] = *(const bf16x8*)(ldsB + bvo[C] + KS * 32768 + 8192 + n * 1024); \
    }                                                                         \
    stageA(N, KS);                                                            \
    S_BARRIER();                                                              \
    LGKM0();                                                                  \
    SCHEDB();                                                                 \
    __builtin_amdgcn_s_setprio(1);                                            \
    _Pragma("unroll") for (int m = 0; m < 4; ++m)                             \
        _Pragma("unroll") for (int n = 0; n < 2; ++n) {                       \
      MFMA16(accg[m][n], a[m], bg[n]);                                        \
      MFMA16(accl[m][n], a[m], bl[n]);                                        \
    }                                                                         \
    __builtin_amdgcn_s_setprio(0);                                            \
    S_BARRIER();                                                              \
    SCHEDB();                                                                 \
    _Pragma("unroll") for (int m = 0; m < 4; ++m)                             \
        a[m] = *(const bf16x8*)(ldsB + avo[C] + KS * 32768 + 4096 + m * 1024);\
    stageB(N, KS);                                                            \
    S_BARRIER();                                                              \
    LGKM0();                                                                  \
    SCHEDB();                                                                 \
    __builtin_amdgcn_s_setprio(1);                                            \
    _Pragma("unroll") for (int m = 0; m < 4; ++m)                             \
        _Pragma("unroll") for (int n = 0; n < 2; ++n) {                       \
      MFMA16(accg[m + 4][n], a[m], bg[n]);                                    \
      MFMA16(accl[m + 4][n], a[m], bl[n]);                                    \
    }                                                                         \
    __builtin_amdgcn_s_setprio(0);                                            \
    WAITV(4);                                                                 \
    S_BARRIER();                                                              \
    SCHEDB();                                                                 \
  }

#define G1_TILE(C, N)  \
  { G1_KHALF(C, N, 0); G1_KHALF(C, N, 1); G1_ADV(); }

  // Prologue: stage tile 0 (A0,B0,A1,B1); WAITV(4) leaves ks1 pair in flight.
  stageA(0, 0); stageB(0, 0); IRFENCE();
  stageA(0, 1); stageB(0, 1);
  G1_ADV();
  WAITV(4);
  S_BARRIER();

  bf16x8 a[4], bg[2], bl[2];
#pragma unroll 1
  for (int it = 0; it < 7; ++it) {  // tiles 0..13
    G1_TILE(0, 1);
    G1_TILE(1, 0);
  }
  G1_TILE(0, 1);  // tile 14, stages tile 15 into buf1

  // Tail: tile 15 in buf1 (ks0 drained by tile14's last WAITV; ks1 in flight).
  {
#pragma unroll
    for (int m = 0; m < 4; ++m)
      a[m] = *(const bf16x8*)(ldsB + avo[1] + m * 1024);
#pragma unroll
    for (int n = 0; n < 2; ++n) {
      bg[n] = *(const bf16x8*)(ldsB + bvo[1] + n * 1024);
      bl[n] = *(const bf16x8*)(ldsB + bvo[1] + 8192 + n * 1024);
    }
#pragma unroll
    for (int m = 0; m < 4; ++m)
#pragma unroll
      for (int n = 0; n < 2; ++n) {
        MFMA16(accg[m][n], a[m], bg[n]);
        MFMA16(accl[m][n], a[m], bl[n]);
      }
#pragma unroll
    for (int m = 0; m < 4; ++m)
      a[m] = *(const bf16x8*)(ldsB + avo[1] + 4096 + m * 1024);
#pragma unroll
    for (int m = 0; m < 4; ++m)
#pragma unroll
      for (int n = 0; n < 2; ++n) {
        MFMA16(accg[m + 4][n], a[m], bg[n]);
        MFMA16(accl[m + 4][n], a[m], bl[n]);
      }
    WAITV(0);
    S_BARRIER();  // all waves' ks1 staging drained
#pragma unroll
    for (int m = 0; m < 4; ++m)
      a[m] = *(const bf16x8*)(ldsB + avo[1] + 32768 + m * 1024);
#pragma unroll
    for (int n = 0; n < 2; ++n) {
      bg[n] = *(const bf16x8*)(ldsB + bvo[1] + 32768 + n * 1024);
      bl[n] = *(const bf16x8*)(ldsB + bvo[1] + 32768 + 8192 + n * 1024);
    }
#pragma unroll
    for (int m = 0; m < 4; ++m)
#pragma unroll
      for (int n = 0; n < 2; ++n) {
        MFMA16(accg[m][n], a[m], bg[n]);
        MFMA16(accl[m][n], a[m], bl[n]);
      }
#pragma unroll
    for (int m = 0; m < 4; ++m)
      a[m] = *(const bf16x8*)(ldsB + avo[1] + 32768 + 4096 + m * 1024);
#pragma unroll
    for (int m = 0; m < 4; ++m)
#pragma unroll
      for (int n = 0; n < 2; ++n) {
        MFMA16(accg[m + 4][n], a[m], bg[n]);
        MFMA16(accl[m + 4][n], a[m], bl[n]);
      }
  }
#undef G1_KHALF
#undef G1_TILE
#undef G1_ADV

  // Epilogue: bias + clip + sigmoid-gate, store bf16 act.
  const float* b1e = b1 + (size_t)e * 2 * I_DIM;
#pragma unroll
  for (int m = 0; m < 8; ++m)
#pragma unroll
    for (int n = 0; n < 2; ++n) {
      const int gcol = bcol + wn * 32 + n * 16 + r16;
      const float bgb = b1e[gcol];
      const float blb = b1e[I_DIM + gcol];
#pragma unroll
      for (int rr = 0; rr < 4; ++rr) {
        const int grow = brow + wm * 128 + m * 16 + kh * 4 + rr;
        const float hg = accg[m][n][rr] + bgb;
        const float hl = accl[m][n][rr] + blb;
        const float g = fminf(hg, 7.f);
        const float l = fminf(fmaxf(hl, -7.f), 7.f);
        const float s = 1.f / (1.f + __expf(-1.702f * g));
        const float av = g * s * (l + 1.f);
        act[((size_t)e * T_DIM + grow) * I_DIM + gcol] = f32_to_bf16(av);
      }
    }
}

// ---------------- GEMM2: 256x128, split-K=2 (expert), same 4-phase structure ---
// 8 waves 2x4, per-wave 128x32 (acc 8x2). Units/K-tile: A(2 loads)+B(1) per
// k-half -> WAITV(3) at the two k-half boundaries. LDS 96KB.
__global__ __launch_bounds__(512, 2) void k_gemm2(
    const ushort_t* __restrict__ act, const ushort_t* __restrict__ w2T,
    float* __restrict__ out) {
  __shared__ __align__(16) ushort_t lds[2][2][12288];  // 96 KiB
  char* const ldsB = (char*)&lds[0][0][0];
  const int tid = threadIdx.x;
  const int wg = (blockIdx.x & 7) * 32 + (blockIdx.x >> 3);
  const int e = wg >> 7;
  const int tileid = wg & 127;
  const int brow = (tileid >> 3) * 256;
  const int bcol = (tileid & 7) * 128;
  const int lane = tid & 63;
  const int wid = tid >> 6;
  const int wm = wid >> 2;   // 0..1
  const int wn = wid & 3;    // 0..3
  const int r16 = lane & 15, kh = lane >> 4;

  const ushort_t* aBase = act + ((size_t)e * T_DIM + brow) * I_DIM;
  const ushort_t* bBase = w2T + ((size_t)e * H_DIM + bcol) * I_DIM;

  f32x4 acc[8][2];
  const f32x4 zf = {0.f, 0.f, 0.f, 0.f};
#pragma unroll
  for (int m = 0; m < 8; ++m)
#pragma unroll
    for (int n = 0; n < 2; ++n) acc[m][n] = zf;

  int srow[2], scolb[2];
#pragma unroll
  for (int j = 0; j < 2; ++j) {
    const int u = swz((j * 512 + tid) * 16);
    srow[j] = u >> 6;
    scolb[j] = (u & 63) >> 1;
  }
  const int ldst0 = (tid & ~63) * 16;

  const ushort_t* pA0 = aBase + (size_t)srow[0] * I_DIM + scolb[0];
  const ushort_t* pA1 = aBase + (size_t)srow[1] * I_DIM + scolb[1];
  const ushort_t* pB = bBase + (size_t)srow[0] * I_DIM + scolb[0];

  int avo[2], bvo[2];
  {
    const int abase = swz((wm * 128 + r16) * 64 + kh * 16);
    const int bbase = 16384 + swz((wn * 32 + r16) * 64 + kh * 16);
#pragma unroll
    for (int bq = 0; bq < 2; ++bq) {
      avo[bq] = bq * 49152 + abase;
      bvo[bq] = bq * 49152 + bbase;
    }
  }

  auto stageA = [&](int buf, int ks) {
    gload_lds16(pA0 + ks * 32, ldsB + buf * 49152 + ks * 24576 + ldst0);
    gload_lds16(pA1 + ks * 32, ldsB + buf * 49152 + ks * 24576 + 8192 + ldst0);
  };
  auto stageB = [&](int buf, int ks) {
    gload_lds16(pB + ks * 32, ldsB + buf * 49152 + ks * 24576 + 16384 + ldst0);
  };

#define G2_ADV() \
  { pA0 += 64; pA1 += 64; pB += 64; }

#define G2_KHALF(C, N, KS)                                                    \
  {                                                                           \
    _Pragma("unroll") for (int m = 0; m < 4; ++m)                             \
        a[m] = *(const bf16x8*)(ldsB + avo[C] + KS * 24576 + m * 1024);       \
    _Pragma("unroll") for (int n = 0; n < 2; ++n)                             \
        b[n] = *(const bf16x8*)(ldsB + bvo[C] + KS * 24576 + n * 1024);       \
    stageA(N, KS);                                                            \
    S_BARRIER();                                                              \
    LGKM0();                                                                  \
    SCHEDB();                                                                 \
    __builtin_amdgcn_s_setprio(1);                                            \
    _Pragma("unroll") for (int m = 0; m < 4; ++m)                             \
        _Pragma("unroll") for (int n = 0; n < 2; ++n)                         \
            MFMA16(acc[m][n], a[m], b[n]);                                    \
    __builtin_amdgcn_s_setprio(0);                                            \
    S_BARRIER();                                                              \
    SCHEDB();                                                                 \
    _Pragma("unroll") for (int m = 0; m < 4; ++m)                             \
        a[m] = *(const bf16x8*)(ldsB + avo[C] + KS * 24576 + 4096 + m * 1024);\
    stageB(N, KS);                                                            \
    S_BARRIER();                                                              \
    LGKM0();                                                                  \
    SCHEDB();                                                                 \
    __builtin_amdgcn_s_setprio(1);                                            \
    _Pragma("unroll") for (int m = 0; m < 4; ++m)                             \
        _Pragma("unroll") for (int n = 0; n < 2; ++n)                         \
            MFMA16(acc[m + 4][n], a[m], b[n]);                                \
    __builtin_amdgcn_s_setprio(0);                                            \
    WAITV(3);                                                                 \
    S_BARRIER();                                                              \
    SCHEDB();                                                                 \
  }

#define G2_TILE(C, N)  \
  { G2_KHALF(C, N, 0); G2_KHALF(C, N, 1); G2_ADV(); }

  // Prologue.
  stageA(0, 0); stageB(0, 0); IRFENCE();
  stageA(0, 1); stageB(0, 1);
  G2_ADV();
  WAITV(3);
  S_BARRIER();

  bf16x8 a[4], b[2];
#pragma unroll 1
  for (int it = 0; it < 15; ++it) {  // tiles 0..29
    G2_TILE(0, 1);
    G2_TILE(1, 0);
  }
  G2_TILE(0, 1);  // tile 30, stages 31 into buf1

  // Tail: tile 31 in buf1.
  {
#pragma unroll
    for (int m = 0; m < 4; ++m)
      a[m] = *(const bf16x8*)(ldsB + avo[1] + m * 1024);
#pragma unroll
    for (int n = 0; n < 2; ++n)
      b[n] = *(const bf16x8*)(ldsB + bvo[1] + n * 1024);
#pragma unroll
    for (int m = 0; m < 4; ++m)
#pragma unroll
      for (int n = 0; n < 2; ++n) MFMA16(acc[m][n], a[m], b[n]);
#pragma unroll
    for (int m = 0; m < 4; ++m)
      a[m] = *(const bf16x8*)(ldsB + avo[1] + 4096 + m * 1024);
#pragma unroll
    for (int m = 0; m < 4; ++m)
#pragma unroll
      for (int n = 0; n < 2; ++n) MFMA16(acc[m + 4][n], a[m], b[n]);
    WAITV(0);
    S_BARRIER();
#pragma unroll
    for (int m = 0; m < 4; ++m)
      a[m] = *(const bf16x8*)(ldsB + avo[1] + 24576 + m * 1024);
#pragma unroll
    for (int n = 0; n < 2; ++n)
      b[n] = *(const bf16x8*)(ldsB + bvo[1] + 24576 + n * 1024);
#pragma unroll
    for (int m = 0; m < 4; ++m)
#pragma unroll
      for (int n = 0; n < 2; ++n) MFMA16(acc[m][n], a[m], b[n]);
#pragma unroll
    for (int m = 0; m < 4; ++m)
      a[m] = *(const bf16x8*)(ldsB + avo[1] + 24576 + 4096 + m * 1024);
#pragma unroll
    for (int m = 0; m < 4; ++m)
#pragma unroll
      for (int n = 0; n < 2; ++n) MFMA16(acc[m + 4][n], a[m], b[n]);
  }
#undef G2_KHALF
#undef G2_TILE
#undef G2_ADV

  // Epilogue: atomic accumulate 0.5*acc into out (pre-initialized x + bias).
#pragma unroll
  for (int m = 0; m < 8; ++m)
#pragma unroll
    for (int n = 0; n < 2; ++n) {
      const int gcol = bcol + wn * 32 + n * 16 + r16;
#pragma unroll
      for (int rr = 0; rr < 4; ++rr) {
        const int grow = brow + wm * 128 + m * 16 + kh * 4 + rr;
        atomicAdd(&out[(size_t)grow * H_DIM + gcol], 0.5f * acc[m][n][rr]);
      }
    }
}

extern "C" void kernel_launch(void* const* d_in, const int* in_sizes, int n_in,
                              void* d_out, int out_size, void* d_ws, size_t ws_size,
                              hipStream_t stream) {
  const float* x = (const float*)d_in[0];
  const float* scale = (const float*)d_in[1];
  // d_in[2]=gate_kernel, d_in[3]=gate_bias: static routing, logits unused.
  const float* w1 = (const float*)d_in[4];
  const float* b1 = (const float*)d_in[5];
  const float* w2 = (const float*)d_in[6];
  const float* b2 = (const float*)d_in[7];
  float* out = (float*)d_out;

  ushort_t* ws = (ushort_t*)d_ws;
  ushort_t* normed = ws;                                    // [T][H]
  ushort_t* w1T = normed + (size_t)T_DIM * H_DIM;           // [2][2I][H]
  ushort_t* w2T = w1T + (size_t)2 * 2 * I_DIM * H_DIM;      // [2][H][I]
  ushort_t* actb = w2T + (size_t)2 * H_DIM * I_DIM;         // [2][T][I]

  k_rmsnorm_init<<<dim3(T_DIM), 256, 0, stream>>>(x, scale, b2, normed, out);
  k_transpose_cvt<<<dim3(2 * I_DIM / 32, H_DIM / 32, 2), 256, 0, stream>>>(
      w1, w1T, H_DIM, 2 * I_DIM);
  k_transpose_cvt<<<dim3(H_DIM / 32, I_DIM / 32, 2), 256, 0, stream>>>(
      w2, w2T, I_DIM, H_DIM);
  k_gemm1<<<dim3(512), 512, 0, stream>>>(normed, w1T, b1, actb);
  k_gemm2<<<dim3(256), 512, 0, stream>>>(actb, w2T, out);
}